// Round 6
// baseline (352.096 us; speedup 1.0000x reference)
//
#include <hip/hip_runtime.h>

#define NN 50000
#define DD 128
#define NE 600000
#define NP 200000
#define NS 300000
#define NU 256
#define NBH 128
#define EPB 4688   // ceil(NE/NBH)
#define NW 12500   // NN/4 byte-packed words
#define NB64 782   // ceil(NN/64)

typedef __attribute__((ext_vector_type(8))) short short8;
typedef __attribute__((ext_vector_type(4))) float floatx4;

__device__ inline float bf2f(unsigned int u16) {
    unsigned int x = u16 << 16;
    float f; __builtin_memcpy(&f, &x, 4); return f;
}
__device__ inline unsigned short f2bf(float f) {
    unsigned int x; __builtin_memcpy(&x, &f, 4);
    unsigned int lsb = (x >> 16) & 1u;
    x += 0x7fffu + lsb;
    return (unsigned short)(x >> 16);
}

// ---- per-block byte histograms: grid (NBH, 2); y=0 counts src, y=1 counts dst ----
__global__ __launch_bounds__(256) void k_hist(const int* __restrict__ ei,
                                              unsigned int* __restrict__ P) {
    __shared__ unsigned int hw[NW];
    int b = blockIdx.x, half = blockIdx.y, tid = threadIdx.x;
    for (int w = tid; w < NW; w += 256) hw[w] = 0;
    __syncthreads();
    const int* src = ei + (size_t)half * NE;
    int e0 = b * EPB, e1 = min(e0 + EPB, NE);
    for (int e = e0 + tid; e < e1; e += 256) {
        int s = src[e];
        atomicAdd(&hw[s >> 2], 1u << ((s & 3) * 8));
    }
    __syncthreads();
    unsigned int* Pb = P + ((size_t)half * NBH + b) * NW;
    for (int w = tid; w < NW; w += 256) Pb[w] = hw[w];
}

// ---- reduce partials -> deg_in ints + rsqrt for both halves ----
__global__ void k_reduce(const unsigned int* __restrict__ P, int* __restrict__ deg_in,
                         float* __restrict__ r) {
    int w = blockIdx.x * 256 + threadIdx.x;
    if (w >= 2 * NW) return;
    int half = (w >= NW);
    int wl = w - half * NW;
    const unsigned int* Ph = P + (size_t)half * NBH * NW + wl;
    int c0 = 0, c1 = 0, c2 = 0, c3 = 0;
    for (int b = 0; b < NBH; ++b) {
        unsigned int v = Ph[(size_t)b * NW];
        c0 += v & 0xff; c1 += (v >> 8) & 0xff; c2 += (v >> 16) & 0xff; c3 += v >> 24;
    }
    int nb = wl * 4;
    if (half) {
        int4 d = {c0, c1, c2, c3};
        *(int4*)(deg_in + nb) = d;
    }
    float4 rr = {rsqrtf((float)max(c0, 1)), rsqrtf((float)max(c1, 1)),
                 rsqrtf((float)max(c2, 1)), rsqrtf((float)max(c3, 1))};
    *(float4*)(r + (size_t)half * NN + nb) = rr;
}

// ---- single-block exclusive prefix sum (int4-wide) of deg_in -> row_ptr[NN+1] ----
__global__ __launch_bounds__(1024) void k_scan(const int* __restrict__ deg_in,
                                               int* __restrict__ row_ptr) {
    __shared__ int wsum[16];
    __shared__ int woff[16];
    __shared__ int carry_s;
    __shared__ int total_s;
    int tid = threadIdx.x, lane = tid & 63, w = tid >> 6;
    if (tid == 0) carry_s = 0;
    __syncthreads();
    for (int wb = 0; wb < NW; wb += 1024) {
        int i4 = wb + tid;
        int4 v = {0, 0, 0, 0};
        if (i4 < NW) v = *(const int4*)(deg_in + i4 * 4);
        int t0 = v.x, t1 = t0 + v.y, t2 = t1 + v.z, tot = t2 + v.w;
        int x = tot;
#pragma unroll
        for (int off = 1; off < 64; off <<= 1) {
            int y = __shfl_up(x, off);
            if (lane >= off) x += y;
        }
        if (lane == 63) wsum[w] = x;
        __syncthreads();
        if (w == 0 && lane < 16) {
            int s = wsum[lane];
            int xs = s;
#pragma unroll
            for (int off = 1; off < 16; off <<= 1) {
                int y = __shfl_up(xs, off);
                if (lane >= off) xs += y;
            }
            woff[lane] = xs - s;
            if (lane == 15) total_s = xs;
        }
        __syncthreads();
        if (i4 < NW) {
            int base = carry_s + woff[w] + x - tot;
            int4 o = {base, base + t0, base + t1, base + t2};
            *(int4*)(row_ptr + i4 * 4) = o;
        }
        __syncthreads();
        if (tid == 0) carry_s += total_s;
        __syncthreads();
    }
    if (tid == 0) row_ptr[NN] = carry_s;
}

// ---- per-(block,node) exclusive base offsets for counting-sort ----
__global__ void k_colscan(const unsigned int* __restrict__ Pin, const int* __restrict__ row_ptr,
                          int* __restrict__ basetab) {
    int n = blockIdx.x * 256 + threadIdx.x;
    if (n >= NN) return;
    int wl = n >> 2, sh = (n & 3) * 8;
    int run = row_ptr[n];
    for (int b = 0; b < NBH; ++b) {
        basetab[(size_t)b * NN + n] = run;
        run += (Pin[(size_t)b * NW + wl] >> sh) & 0xff;
    }
}

// ---- bucket edges, no global atomics: LDS byte cursor + per-block base ----
__global__ __launch_bounds__(256) void k_bucket2(const int* __restrict__ ei,
                                                 const int* __restrict__ basetab,
                                                 int* __restrict__ col) {
    __shared__ unsigned int cw[NW];
    int b = blockIdx.x, tid = threadIdx.x;
    for (int w = tid; w < NW; w += 256) cw[w] = 0;
    __syncthreads();
    const int* bt = basetab + (size_t)b * NN;
    int e0 = b * EPB, e1 = min(e0 + EPB, NE);
    for (int e = e0 + tid; e < e1; e += 256) {
        int s = ei[e], d = ei[NE + e];
        int sh = (d & 3) * 8;
        unsigned int old = atomicAdd(&cw[d >> 2], 1u << sh);
        int local = (old >> sh) & 0xff;
        col[bt[d] + local] = s;
    }
}

// ---- merged transpose + bf16-cast of W1, W2, dW ----
__global__ void k_castW(const float* __restrict__ W1, const float* __restrict__ W2,
                        const float* __restrict__ dW, unsigned short* __restrict__ BT1,
                        unsigned short* __restrict__ BT2, unsigned short* __restrict__ BTd) {
    int t = blockIdx.x * 256 + threadIdx.x;
    if (t < 16384) {
        int r = t >> 7, c = t & 127;
        BT1[c * 128 + r] = f2bf(W1[t]);
    } else if (t < 32768) {
        int t2 = t - 16384;
        int r = t2 >> 7, c = t2 & 127;
        BT2[c * 128 + r] = f2bf(W2[t2]);
    } else if (t < 65536) {
        int t2 = t - 32768;
        int r = t2 >> 8, c = t2 & 255;
        BTd[c * 128 + r] = f2bf(dW[t2]);
    }
}

// ---- layer-1 GEMM: t[64x128 bf16] = (A_f32 @ W1) * r_out ----
__global__ __launch_bounds__(256) void k_gemm1(const float* __restrict__ A,
                                               const float* __restrict__ rs,
                                               const unsigned short* __restrict__ BT,
                                               unsigned short* __restrict__ Cm) {
    __shared__ unsigned short As[64][136];
    __shared__ unsigned short Bs[128][136];
    int tid = threadIdx.x, lane = tid & 63, wave = tid >> 6;
    int quad = lane >> 4, l16 = lane & 15;
    int row0 = blockIdx.x * 64;

#pragma unroll
    for (int p = 0; p < 8; ++p) {
        int fid = tid + p * 256;
        int r = fid >> 5, c = fid & 31;
        int gr = row0 + r; if (gr > NN - 1) gr = NN - 1;
        float4 v = *(const float4*)(A + (size_t)gr * DD + c * 4);
        ushort4 u;
        u.x = f2bf(v.x); u.y = f2bf(v.y); u.z = f2bf(v.z); u.w = f2bf(v.w);
        *(ushort4*)&As[r][c * 4] = u;
    }
#pragma unroll
    for (int p = 0; p < 8; ++p) {
        int fid = tid + p * 256;
        int r = fid >> 4, c = fid & 15;
        *(uint4*)&Bs[r][c * 8] = *(const uint4*)(BT + (size_t)r * DD + c * 8);
    }
    __syncthreads();

    short8 af[4];
#pragma unroll
    for (int ks = 0; ks < 4; ++ks)
        af[ks] = *(const short8*)&As[wave * 16 + l16][ks * 32 + quad * 8];
    floatx4 acc[8];
#pragma unroll
    for (int nt = 0; nt < 8; ++nt) acc[nt] = (floatx4){0.f, 0.f, 0.f, 0.f};
#pragma unroll
    for (int ks = 0; ks < 4; ++ks) {
#pragma unroll
        for (int nt = 0; nt < 8; ++nt) {
            short8 bf = *(const short8*)&Bs[nt * 16 + l16][ks * 32 + quad * 8];
            acc[nt] = __builtin_amdgcn_mfma_f32_16x16x32_bf16(af[ks], bf, acc[nt], 0, 0, 0);
        }
    }
    int rbase = row0 + wave * 16 + quad * 4;
#pragma unroll
    for (int r = 0; r < 4; ++r) {
        int gr = rbase + r;
        if (gr < NN) {
            float s = rs[gr];
#pragma unroll
            for (int nt = 0; nt < 8; ++nt)
                Cm[(size_t)gr * DD + nt * 16 + l16] = f2bf(acc[nt][r] * s);
        }
    }
}

// ---- aggregation phase (device helper): wave aggregates its 16 rows into As ----
// As row = bf16(sum_{s in N(node)} T[s] * r_in[node] + bias)
__device__ inline void agg_into_As(const unsigned short* __restrict__ T,
                                   const int* __restrict__ row_ptr,
                                   const int* __restrict__ col,
                                   const float* __restrict__ r_in,
                                   const float* __restrict__ bias,
                                   unsigned short (*As)[136],
                                   int row0, int lane, int wave) {
    float2 breg = *(const float2*)(bias + lane * 2);
#pragma unroll 1
    for (int i = 0; i < 16; ++i) {
        int node = row0 + wave * 16 + i;
        int cn = min(node, NN - 1);
        int beg = row_ptr[cn], end = row_ptr[cn + 1];
        float a0 = 0.f, a1 = 0.f;
        for (int base = beg; base < end; base += 64) {
            int m = end - base; if (m > 64) m = 64;
            int myidx = (lane < m) ? col[base + lane] : 0;
            int j = 0;
            for (; j + 4 <= m; j += 4) {
                int s0 = __shfl(myidx, j), s1 = __shfl(myidx, j + 1);
                int s2 = __shfl(myidx, j + 2), s3 = __shfl(myidx, j + 3);
                unsigned int v0 = *(const unsigned int*)(T + (size_t)s0 * DD + lane * 2);
                unsigned int v1 = *(const unsigned int*)(T + (size_t)s1 * DD + lane * 2);
                unsigned int v2 = *(const unsigned int*)(T + (size_t)s2 * DD + lane * 2);
                unsigned int v3 = *(const unsigned int*)(T + (size_t)s3 * DD + lane * 2);
                a0 += bf2f(v0 & 0xffff) + bf2f(v1 & 0xffff) + bf2f(v2 & 0xffff) + bf2f(v3 & 0xffff);
                a1 += bf2f(v0 >> 16) + bf2f(v1 >> 16) + bf2f(v2 >> 16) + bf2f(v3 >> 16);
            }
            for (; j < m; ++j) {
                int s = __shfl(myidx, j);
                unsigned int v = *(const unsigned int*)(T + (size_t)s * DD + lane * 2);
                a0 += bf2f(v & 0xffff);
                a1 += bf2f(v >> 16);
            }
        }
        float rv = r_in[cn];
        unsigned int packed = (unsigned int)f2bf(a0 * rv + breg.x) |
                              ((unsigned int)f2bf(a1 * rv + breg.y) << 16);
        *(unsigned int*)&As[wave * 16 + i][lane * 2] = packed;
    }
}

// ---- fused: h1 = aggregate(t)+finalize -> t2 = (h1 @ W2) * r_out ----
__global__ __launch_bounds__(256) void k_agg_gemm(const unsigned short* __restrict__ T,
                                                  const int* __restrict__ row_ptr,
                                                  const int* __restrict__ col,
                                                  const float* __restrict__ r_in,
                                                  const float* __restrict__ bias,
                                                  const float* __restrict__ rs,
                                                  const unsigned short* __restrict__ BT,
                                                  unsigned short* __restrict__ Cm) {
    __shared__ unsigned short As[64][136];
    __shared__ unsigned short Bs[128][136];
    int tid = threadIdx.x, lane = tid & 63, wave = tid >> 6;
    int quad = lane >> 4, l16 = lane & 15;
    int row0 = blockIdx.x * 64;

    // prefetch W2 tile into registers; loads overlap the aggregation gathers
    uint4 breg[8];
#pragma unroll
    for (int p = 0; p < 8; ++p) {
        int fid = tid + p * 256;
        int r = fid >> 4, c = fid & 15;
        breg[p] = *(const uint4*)(BT + (size_t)r * DD + c * 8);
    }

    agg_into_As(T, row_ptr, col, r_in, bias, As, row0, lane, wave);

#pragma unroll
    for (int p = 0; p < 8; ++p) {
        int fid = tid + p * 256;
        int r = fid >> 4, c = fid & 15;
        *(uint4*)&Bs[r][c * 8] = breg[p];
    }
    __syncthreads();

    short8 af[4];
#pragma unroll
    for (int ks = 0; ks < 4; ++ks)
        af[ks] = *(const short8*)&As[wave * 16 + l16][ks * 32 + quad * 8];
    floatx4 acc[8];
#pragma unroll
    for (int nt = 0; nt < 8; ++nt) acc[nt] = (floatx4){0.f, 0.f, 0.f, 0.f};
#pragma unroll
    for (int ks = 0; ks < 4; ++ks) {
#pragma unroll
        for (int nt = 0; nt < 8; ++nt) {
            short8 bf = *(const short8*)&Bs[nt * 16 + l16][ks * 32 + quad * 8];
            acc[nt] = __builtin_amdgcn_mfma_f32_16x16x32_bf16(af[ks], bf, acc[nt], 0, 0, 0);
        }
    }
    int rbase = row0 + wave * 16 + quad * 4;
#pragma unroll
    for (int r = 0; r < 4; ++r) {
        int gr = rbase + r;
        if (gr < NN) {
            float s = rs[gr];
#pragma unroll
            for (int nt = 0; nt < 8; ++nt)
                Cm[(size_t)gr * DD + nt * 16 + l16] = f2bf(acc[nt][r] * s);
        }
    }
}

// ---- fused: h2 = aggregate(t2)+finalize -> P = softmax(relu(h2@dW+db)@oW+ob) ----
__global__ __launch_bounds__(256) void k_agg_mlp(const unsigned short* __restrict__ T,
                                                 const int* __restrict__ row_ptr,
                                                 const int* __restrict__ col,
                                                 const float* __restrict__ r_in,
                                                 const float* __restrict__ bias,
                                                 const unsigned short* __restrict__ BTd,
                                                 const float* __restrict__ db,
                                                 const float* __restrict__ oW,
                                                 const float* __restrict__ ob,
                                                 float* __restrict__ P) {
    __shared__ unsigned short As[64][136];
    __shared__ unsigned short Bs[128][136];
    int tid = threadIdx.x, lane = tid & 63, wave = tid >> 6;
    int quad = lane >> 4, l16 = lane & 15;
    int row0 = blockIdx.x * 64;

    // prefetch dense-W chunk 0
    uint4 breg[8];
#pragma unroll
    for (int p = 0; p < 8; ++p) {
        int fid = tid + p * 256;
        int r = fid >> 4, c = fid & 15;
        breg[p] = *(const uint4*)(BTd + (size_t)r * DD + c * 8);
    }

    agg_into_As(T, row_ptr, col, r_in, bias, As, row0, lane, wave);

#pragma unroll
    for (int p = 0; p < 8; ++p) {
        int fid = tid + p * 256;
        int r = fid >> 4, c = fid & 15;
        *(uint4*)&Bs[r][c * 8] = breg[p];
    }
    __syncthreads();

    short8 af[4];
#pragma unroll
    for (int ks = 0; ks < 4; ++ks)
        af[ks] = *(const short8*)&As[wave * 16 + l16][ks * 32 + quad * 8];
    floatx4 acc[16];
#pragma unroll
    for (int i = 0; i < 16; ++i) acc[i] = (floatx4){0.f, 0.f, 0.f, 0.f};
#pragma unroll
    for (int ks = 0; ks < 4; ++ks) {
#pragma unroll
        for (int nt = 0; nt < 8; ++nt) {
            short8 bf = *(const short8*)&Bs[nt * 16 + l16][ks * 32 + quad * 8];
            acc[nt] = __builtin_amdgcn_mfma_f32_16x16x32_bf16(af[ks], bf, acc[nt], 0, 0, 0);
        }
    }
    __syncthreads();   // chunk-0 Bs readers done
#pragma unroll
    for (int p = 0; p < 8; ++p) {
        int fid = tid + p * 256;
        int r = fid >> 4, c = fid & 15;
        *(uint4*)&Bs[r][c * 8] = *(const uint4*)(BTd + (size_t)(128 + r) * DD + c * 8);
    }
    __syncthreads();
#pragma unroll
    for (int ks = 0; ks < 4; ++ks) {
#pragma unroll
        for (int nt = 0; nt < 8; ++nt) {
            short8 bf = *(const short8*)&Bs[nt * 16 + l16][ks * 32 + quad * 8];
            acc[8 + nt] = __builtin_amdgcn_mfma_f32_16x16x32_bf16(af[ks], bf, acc[8 + nt], 0, 0, 0);
        }
    }
    // fused bias+relu+output-layer+softmax
    int rbase = row0 + wave * 16 + quad * 4;
#pragma unroll
    for (int r = 0; r < 4; ++r) {
        float p0 = 0.f, p1 = 0.f;
#pragma unroll
        for (int ch = 0; ch < 2; ++ch) {
#pragma unroll
            for (int nt = 0; nt < 8; ++nt) {
                int colc = ch * 128 + nt * 16 + l16;
                float h = acc[ch * 8 + nt][r] + db[colc];
                h = fmaxf(h, 0.f);
                p0 += h * oW[2 * colc];
                p1 += h * oW[2 * colc + 1];
            }
        }
#pragma unroll
        for (int m = 8; m >= 1; m >>= 1) {
            p0 += __shfl_xor(p0, m, 16);
            p1 += __shfl_xor(p1, m, 16);
        }
        if (l16 == 0) {
            int gr = rbase + r;
            if (gr < NN) {
                float l0 = p0 + ob[0], l1 = p1 + ob[1];
                float mx = fmaxf(l0, l1);
                float e0 = __expf(l0 - mx), e1 = __expf(l1 - mx);
                float inv = 1.f / (e0 + e1);
                float2 pr = {e0 * inv, e1 * inv};
                *(float2*)(P + 2 * gr) = pr;
            }
        }
    }
}

// ---- final gather ----
__global__ void k_gather(const int* __restrict__ sidx, const int* __restrict__ oe,
                         const float* __restrict__ P, float* __restrict__ out) {
    int i = blockIdx.x * 256 + threadIdx.x;
    if (i >= NS) return;
    int node = oe[sidx[i]];
    float2 v = *(const float2*)(P + 2 * node);
    *(float2*)(out + 2 * i) = v;
}

extern "C" void kernel_launch(void* const* d_in, const int* in_sizes, int n_in,
                              void* d_out, int out_size, void* d_ws, size_t ws_size,
                              hipStream_t stream) {
    const float* node_state = (const float*)d_in[0];
    const int* ei   = (const int*)d_in[1];
    const int* oe   = (const int*)d_in[2];
    const int* sidx = (const int*)d_in[3];
    const float* W1 = (const float*)d_in[4];
    const float* b1 = (const float*)d_in[5];
    const float* W2 = (const float*)d_in[6];
    const float* b2 = (const float*)d_in[7];
    const float* dW = (const float*)d_in[8];
    const float* db = (const float*)d_in[9];
    const float* oW = (const float*)d_in[10];
    const float* ob = (const float*)d_in[11];
    float* out = (float*)d_out;

    char* ws = (char*)d_ws;
    size_t off = 0;
    auto carve = [&](size_t bytes) -> char* {
        char* p = ws + off;
        off = (off + bytes + 255) & ~(size_t)255;
        return p;
    };
    int*   deg_in  = (int*)carve((size_t)NN * 4);
    float* r       = (float*)carve((size_t)2 * NN * 4);
    int*   row_ptr = (int*)carve((size_t)(NN + 1) * 4);
    int*   col     = (int*)carve((size_t)NE * 4);
    unsigned int* P_hist = (unsigned int*)carve((size_t)2 * NBH * NW * 4);
    int*   basetab = (int*)carve((size_t)NBH * NN * 4);
    unsigned short* t   = (unsigned short*)carve((size_t)NN * DD * 2);
    unsigned short* t2  = (unsigned short*)carve((size_t)NN * DD * 2);
    unsigned short* BT1 = (unsigned short*)carve((size_t)DD * DD * 2);
    unsigned short* BT2 = (unsigned short*)carve((size_t)DD * DD * 2);
    unsigned short* BTd = (unsigned short*)carve((size_t)DD * NU * 2);
    float* P = (float*)t;   // alias: t dead after k_agg_gemm

    float* r_out = r;
    float* r_in  = r + NN;

    // CSR build — no global atomics
    k_hist<<<dim3(NBH, 2), 256, 0, stream>>>(ei, P_hist);
    k_reduce<<<(2 * NW + 255) / 256, 256, 0, stream>>>(P_hist, deg_in, r);
    k_scan<<<1, 1024, 0, stream>>>(deg_in, row_ptr);
    k_colscan<<<(NN + 255) / 256, 256, 0, stream>>>(P_hist + (size_t)NBH * NW, row_ptr, basetab);
    k_bucket2<<<NBH, 256, 0, stream>>>(ei, basetab, col);

    // weight prep (single kernel)
    k_castW<<<256, 256, 0, stream>>>(W1, W2, dW, BT1, BT2, BTd);

    // layer 1 GEMM
    k_gemm1<<<NB64, 256, 0, stream>>>(node_state, r_out, BT1, t);
    // fused: aggregate(t)+finalize(b1) -> GEMM W2 -> t2
    k_agg_gemm<<<NB64, 256, 0, stream>>>(t, row_ptr, col, r_in, b1, r_out, BT2, t2);
    // fused: aggregate(t2)+finalize(b2) -> dense MLP + softmax -> P
    k_agg_mlp<<<NB64, 256, 0, stream>>>(t2, row_ptr, col, r_in, b2, BTd, db, oW, ob, P);

    // final gather
    k_gather<<<(NS + 255) / 256, 256, 0, stream>>>(sidx, oe, P, out);
}

// Round 7
// 266.916 us; speedup vs baseline: 1.3191x; 1.3191x over previous
//
#include <hip/hip_runtime.h>

#define NN 50000
#define DD 128
#define NE 600000
#define NP 200000
#define NS 300000
#define NU 256
#define NBH 64
#define EPB 9375   // NE/NBH
#define NW 12500   // NN/4 byte-packed words
#define NB64 782   // ceil(NN/64)

typedef __attribute__((ext_vector_type(8))) short short8;
typedef __attribute__((ext_vector_type(4))) float floatx4;

__device__ inline float bf2f(unsigned int u16) {
    unsigned int x = u16 << 16;
    float f; __builtin_memcpy(&f, &x, 4); return f;
}
__device__ inline unsigned short f2bf(float f) {
    unsigned int x; __builtin_memcpy(&x, &f, 4);
    unsigned int lsb = (x >> 16) & 1u;
    x += 0x7fffu + lsb;
    return (unsigned short)(x >> 16);
}

// ---- per-block byte histograms: grid (NBH, 2); y=0 counts src, y=1 counts dst ----
__global__ __launch_bounds__(256) void k_hist(const int* __restrict__ ei,
                                              unsigned int* __restrict__ P) {
    __shared__ unsigned int hw[NW];
    int b = blockIdx.x, half = blockIdx.y, tid = threadIdx.x;
    for (int w = tid; w < NW; w += 256) hw[w] = 0;
    __syncthreads();
    const int* src = ei + (size_t)half * NE;
    int e0 = b * EPB, e1 = min(e0 + EPB, NE);
    for (int e = e0 + tid; e < e1; e += 256) {
        int s = src[e];
        atomicAdd(&hw[s >> 2], 1u << ((s & 3) * 8));
    }
    __syncthreads();
    unsigned int* Pb = P + ((size_t)half * NBH + b) * NW;
    for (int w = tid; w < NW; w += 256) Pb[w] = hw[w];
}

// ---- reduce partials -> deg_in ints + rsqrt for both halves ----
__global__ void k_reduce(const unsigned int* __restrict__ P, int* __restrict__ deg_in,
                         float* __restrict__ r) {
    int w = blockIdx.x * 256 + threadIdx.x;
    if (w >= 2 * NW) return;
    int half = (w >= NW);
    int wl = w - half * NW;
    const unsigned int* Ph = P + (size_t)half * NBH * NW + wl;
    int c0 = 0, c1 = 0, c2 = 0, c3 = 0;
    for (int b = 0; b < NBH; ++b) {
        unsigned int v = Ph[(size_t)b * NW];
        c0 += v & 0xff; c1 += (v >> 8) & 0xff; c2 += (v >> 16) & 0xff; c3 += v >> 24;
    }
    int nb = wl * 4;
    if (half) {
        int4 d = {c0, c1, c2, c3};
        *(int4*)(deg_in + nb) = d;
    }
    float4 rr = {rsqrtf((float)max(c0, 1)), rsqrtf((float)max(c1, 1)),
                 rsqrtf((float)max(c2, 1)), rsqrtf((float)max(c3, 1))};
    *(float4*)(r + (size_t)half * NN + nb) = rr;
}

// ---- single-block exclusive prefix sum (int4-wide) of deg_in -> row_ptr[NN+1] ----
__global__ __launch_bounds__(1024) void k_scan(const int* __restrict__ deg_in,
                                               int* __restrict__ row_ptr) {
    __shared__ int wsum[16];
    __shared__ int woff[16];
    __shared__ int carry_s;
    __shared__ int total_s;
    int tid = threadIdx.x, lane = tid & 63, w = tid >> 6;
    if (tid == 0) carry_s = 0;
    __syncthreads();
    for (int wb = 0; wb < NW; wb += 1024) {
        int i4 = wb + tid;
        int4 v = {0, 0, 0, 0};
        if (i4 < NW) v = *(const int4*)(deg_in + i4 * 4);
        int t0 = v.x, t1 = t0 + v.y, t2 = t1 + v.z, tot = t2 + v.w;
        int x = tot;
#pragma unroll
        for (int off = 1; off < 64; off <<= 1) {
            int y = __shfl_up(x, off);
            if (lane >= off) x += y;
        }
        if (lane == 63) wsum[w] = x;
        __syncthreads();
        if (w == 0 && lane < 16) {
            int s = wsum[lane];
            int xs = s;
#pragma unroll
            for (int off = 1; off < 16; off <<= 1) {
                int y = __shfl_up(xs, off);
                if (lane >= off) xs += y;
            }
            woff[lane] = xs - s;
            if (lane == 15) total_s = xs;
        }
        __syncthreads();
        if (i4 < NW) {
            int base = carry_s + woff[w] + x - tot;
            int4 o = {base, base + t0, base + t1, base + t2};
            *(int4*)(row_ptr + i4 * 4) = o;
        }
        __syncthreads();
        if (tid == 0) carry_s += total_s;
        __syncthreads();
    }
    if (tid == 0) row_ptr[NN] = carry_s;
}

// ---- per-(block,node) exclusive base offsets for counting-sort ----
__global__ void k_colscan(const unsigned int* __restrict__ Pin, const int* __restrict__ row_ptr,
                          int* __restrict__ basetab) {
    int n = blockIdx.x * 256 + threadIdx.x;
    if (n >= NN) return;
    int wl = n >> 2, sh = (n & 3) * 8;
    int run = row_ptr[n];
    for (int b = 0; b < NBH; ++b) {
        basetab[(size_t)b * NN + n] = run;
        run += (Pin[(size_t)b * NW + wl] >> sh) & 0xff;
    }
}

// ---- bucket edges, no global atomics: LDS byte cursor + per-block base ----
__global__ __launch_bounds__(256) void k_bucket2(const int* __restrict__ ei,
                                                 const int* __restrict__ basetab,
                                                 int* __restrict__ col) {
    __shared__ unsigned int cw[NW];
    int b = blockIdx.x, tid = threadIdx.x;
    for (int w = tid; w < NW; w += 256) cw[w] = 0;
    __syncthreads();
    const int* bt = basetab + (size_t)b * NN;
    int e0 = b * EPB, e1 = min(e0 + EPB, NE);
    for (int e = e0 + tid; e < e1; e += 256) {
        int s = ei[e], d = ei[NE + e];
        int sh = (d & 3) * 8;
        unsigned int old = atomicAdd(&cw[d >> 2], 1u << sh);
        int local = (old >> sh) & 0xff;
        col[bt[d] + local] = s;
    }
}

// ---- merged transpose + bf16-cast of W1, W2, dW ----
__global__ void k_castW(const float* __restrict__ W1, const float* __restrict__ W2,
                        const float* __restrict__ dW, unsigned short* __restrict__ BT1,
                        unsigned short* __restrict__ BT2, unsigned short* __restrict__ BTd) {
    int t = blockIdx.x * 256 + threadIdx.x;
    if (t < 16384) {
        int r = t >> 7, c = t & 127;
        BT1[c * 128 + r] = f2bf(W1[t]);
    } else if (t < 32768) {
        int t2 = t - 16384;
        int r = t2 >> 7, c = t2 & 127;
        BT2[c * 128 + r] = f2bf(W2[t2]);
    } else if (t < 65536) {
        int t2 = t - 32768;
        int r = t2 >> 8, c = t2 & 255;
        BTd[c * 128 + r] = f2bf(dW[t2]);
    }
}

// ---- MFMA GEMM: Cm[64x128 bf16] = rowscale(A[64x128]) @ B, BT[128][128] bf16 ----
template <bool ABF>
__global__ __launch_bounds__(256) void k_gemm_bf(const void* __restrict__ Ap,
                                                 const float* __restrict__ rs,
                                                 const unsigned short* __restrict__ BT,
                                                 unsigned short* __restrict__ Cm) {
    __shared__ unsigned short As[64][136];
    __shared__ unsigned short Bs[128][136];
    int tid = threadIdx.x, lane = tid & 63, wave = tid >> 6;
    int quad = lane >> 4, l16 = lane & 15;
    int row0 = blockIdx.x * 64;

    if (ABF) {
        const unsigned short* A = (const unsigned short*)Ap;
#pragma unroll
        for (int p = 0; p < 4; ++p) {
            int fid = tid + p * 256;
            int r = fid >> 4, c = fid & 15;
            int gr = row0 + r; if (gr > NN - 1) gr = NN - 1;
            *(uint4*)&As[r][c * 8] = *(const uint4*)(A + (size_t)gr * DD + c * 8);
        }
    } else {
        const float* A = (const float*)Ap;
#pragma unroll
        for (int p = 0; p < 8; ++p) {
            int fid = tid + p * 256;
            int r = fid >> 5, c = fid & 31;
            int gr = row0 + r; if (gr > NN - 1) gr = NN - 1;
            float4 v = *(const float4*)(A + (size_t)gr * DD + c * 4);
            ushort4 u;
            u.x = f2bf(v.x); u.y = f2bf(v.y); u.z = f2bf(v.z); u.w = f2bf(v.w);
            *(ushort4*)&As[r][c * 4] = u;
        }
    }
#pragma unroll
    for (int p = 0; p < 8; ++p) {
        int fid = tid + p * 256;
        int r = fid >> 4, c = fid & 15;
        *(uint4*)&Bs[r][c * 8] = *(const uint4*)(BT + (size_t)r * DD + c * 8);
    }
    __syncthreads();

    short8 af[4];
#pragma unroll
    for (int ks = 0; ks < 4; ++ks)
        af[ks] = *(const short8*)&As[wave * 16 + l16][ks * 32 + quad * 8];
    floatx4 acc[8];
#pragma unroll
    for (int nt = 0; nt < 8; ++nt) acc[nt] = (floatx4){0.f, 0.f, 0.f, 0.f};
#pragma unroll
    for (int ks = 0; ks < 4; ++ks) {
#pragma unroll
        for (int nt = 0; nt < 8; ++nt) {
            short8 bf = *(const short8*)&Bs[nt * 16 + l16][ks * 32 + quad * 8];
            acc[nt] = __builtin_amdgcn_mfma_f32_16x16x32_bf16(af[ks], bf, acc[nt], 0, 0, 0);
        }
    }
    int rbase = row0 + wave * 16 + quad * 4;
#pragma unroll
    for (int r = 0; r < 4; ++r) {
        int gr = rbase + r;
        if (gr < NN) {
            float s = rs[gr];
#pragma unroll
            for (int nt = 0; nt < 8; ++nt)
                Cm[(size_t)gr * DD + nt * 16 + l16] = f2bf(acc[nt][r] * s);
        }
    }
}

// ---- CSR aggregate + fused finalize: H[n] = bf16((sum T[s]) * r_in[n] + b) ----
// 16 lanes/node (uint4 = 16 B/lane), 4 nodes/wave, 16 nodes/block:
// 4 independent gather streams per wave for memory-level parallelism.
__global__ __launch_bounds__(256) void k_aggregate(const unsigned short* __restrict__ T,
                                                   const int* __restrict__ row_ptr,
                                                   const int* __restrict__ col,
                                                   const float* __restrict__ r_in,
                                                   const float* __restrict__ b,
                                                   unsigned short* __restrict__ H) {
    int wave = threadIdx.x >> 6, lane = threadIdx.x & 63;
    int sub = lane >> 4, l16 = lane & 15;
    int node = blockIdx.x * 16 + wave * 4 + sub;
    if (node >= NN) return;
    int beg = row_ptr[node], end = row_ptr[node + 1];
    float a0 = 0.f, a1 = 0.f, a2 = 0.f, a3 = 0.f, a4 = 0.f, a5 = 0.f, a6 = 0.f, a7 = 0.f;
    for (int base = beg; base < end; base += 16) {
        int m = end - base; if (m > 16) m = 16;
        int myidx = (l16 < m) ? col[base + l16] : 0;
        int j = 0;
        for (; j + 2 <= m; j += 2) {
            int s0 = __shfl(myidx, (sub << 4) | j);
            int s1 = __shfl(myidx, (sub << 4) | (j + 1));
            uint4 v0 = *(const uint4*)(T + (size_t)s0 * DD + l16 * 8);
            uint4 v1 = *(const uint4*)(T + (size_t)s1 * DD + l16 * 8);
            a0 += bf2f(v0.x & 0xffff) + bf2f(v1.x & 0xffff);
            a1 += bf2f(v0.x >> 16)    + bf2f(v1.x >> 16);
            a2 += bf2f(v0.y & 0xffff) + bf2f(v1.y & 0xffff);
            a3 += bf2f(v0.y >> 16)    + bf2f(v1.y >> 16);
            a4 += bf2f(v0.z & 0xffff) + bf2f(v1.z & 0xffff);
            a5 += bf2f(v0.z >> 16)    + bf2f(v1.z >> 16);
            a6 += bf2f(v0.w & 0xffff) + bf2f(v1.w & 0xffff);
            a7 += bf2f(v0.w >> 16)    + bf2f(v1.w >> 16);
        }
        if (j < m) {
            int s0 = __shfl(myidx, (sub << 4) | j);
            uint4 v0 = *(const uint4*)(T + (size_t)s0 * DD + l16 * 8);
            a0 += bf2f(v0.x & 0xffff); a1 += bf2f(v0.x >> 16);
            a2 += bf2f(v0.y & 0xffff); a3 += bf2f(v0.y >> 16);
            a4 += bf2f(v0.z & 0xffff); a5 += bf2f(v0.z >> 16);
            a6 += bf2f(v0.w & 0xffff); a7 += bf2f(v0.w >> 16);
        }
    }
    float rv = r_in[node];
    float4 bl = *(const float4*)(b + l16 * 8);
    float4 bh = *(const float4*)(b + l16 * 8 + 4);
    uint4 w;
    w.x = (unsigned int)f2bf(a0 * rv + bl.x) | ((unsigned int)f2bf(a1 * rv + bl.y) << 16);
    w.y = (unsigned int)f2bf(a2 * rv + bl.z) | ((unsigned int)f2bf(a3 * rv + bl.w) << 16);
    w.z = (unsigned int)f2bf(a4 * rv + bh.x) | ((unsigned int)f2bf(a5 * rv + bh.y) << 16);
    w.w = (unsigned int)f2bf(a6 * rv + bh.z) | ((unsigned int)f2bf(a7 * rv + bh.w) << 16);
    *(uint4*)(H + (size_t)node * DD + l16 * 8) = w;
}

// ---- MFMA MLP: P[n] = softmax(relu(h2[n]@dW + db)@oW + ob) ----
__global__ __launch_bounds__(256) void k_mlp_mfma(const unsigned short* __restrict__ H2,
                                                  const unsigned short* __restrict__ BTd,
                                                  const float* __restrict__ db,
                                                  const float* __restrict__ oW,
                                                  const float* __restrict__ ob,
                                                  float* __restrict__ P) {
    __shared__ unsigned short As[64][136];
    __shared__ unsigned short Bs[128][136];
    int tid = threadIdx.x, lane = tid & 63, wave = tid >> 6;
    int quad = lane >> 4, l16 = lane & 15;
    int row0 = blockIdx.x * 64;
#pragma unroll
    for (int p = 0; p < 4; ++p) {
        int fid = tid + p * 256;
        int r = fid >> 4, c = fid & 15;
        int gr = row0 + r; if (gr > NN - 1) gr = NN - 1;
        *(uint4*)&As[r][c * 8] = *(const uint4*)(H2 + (size_t)gr * DD + c * 8);
    }
    short8 af[4];
    floatx4 acc[16];
#pragma unroll
    for (int i = 0; i < 16; ++i) acc[i] = (floatx4){0.f, 0.f, 0.f, 0.f};

    for (int ch = 0; ch < 2; ++ch) {
        __syncthreads();
#pragma unroll
        for (int p = 0; p < 8; ++p) {
            int fid = tid + p * 256;
            int r = fid >> 4, c = fid & 15;
            *(uint4*)&Bs[r][c * 8] = *(const uint4*)(BTd + (size_t)(ch * 128 + r) * DD + c * 8);
        }
        __syncthreads();
        if (ch == 0) {
#pragma unroll
            for (int ks = 0; ks < 4; ++ks)
                af[ks] = *(const short8*)&As[wave * 16 + l16][ks * 32 + quad * 8];
        }
#pragma unroll
        for (int ks = 0; ks < 4; ++ks) {
#pragma unroll
            for (int nt = 0; nt < 8; ++nt) {
                short8 bf = *(const short8*)&Bs[nt * 16 + l16][ks * 32 + quad * 8];
                acc[ch * 8 + nt] =
                    __builtin_amdgcn_mfma_f32_16x16x32_bf16(af[ks], bf, acc[ch * 8 + nt], 0, 0, 0);
            }
        }
    }
    int rbase = row0 + wave * 16 + quad * 4;
#pragma unroll
    for (int r = 0; r < 4; ++r) {
        float p0 = 0.f, p1 = 0.f;
#pragma unroll
        for (int ch = 0; ch < 2; ++ch) {
#pragma unroll
            for (int nt = 0; nt < 8; ++nt) {
                int colc = ch * 128 + nt * 16 + l16;
                float h = acc[ch * 8 + nt][r] + db[colc];
                h = fmaxf(h, 0.f);
                p0 += h * oW[2 * colc];
                p1 += h * oW[2 * colc + 1];
            }
        }
#pragma unroll
        for (int m = 8; m >= 1; m >>= 1) {
            p0 += __shfl_xor(p0, m, 16);
            p1 += __shfl_xor(p1, m, 16);
        }
        if (l16 == 0) {
            int gr = rbase + r;
            if (gr < NN) {
                float l0 = p0 + ob[0], l1 = p1 + ob[1];
                float mx = fmaxf(l0, l1);
                float e0 = __expf(l0 - mx), e1 = __expf(l1 - mx);
                float inv = 1.f / (e0 + e1);
                float2 pr = {e0 * inv, e1 * inv};
                *(float2*)(P + 2 * gr) = pr;
            }
        }
    }
}

// ---- final gather ----
__global__ void k_gather(const int* __restrict__ sidx, const int* __restrict__ oe,
                         const float* __restrict__ P, float* __restrict__ out) {
    int i = blockIdx.x * 256 + threadIdx.x;
    if (i >= NS) return;
    int node = oe[sidx[i]];
    float2 v = *(const float2*)(P + 2 * node);
    *(float2*)(out + 2 * i) = v;
}

extern "C" void kernel_launch(void* const* d_in, const int* in_sizes, int n_in,
                              void* d_out, int out_size, void* d_ws, size_t ws_size,
                              hipStream_t stream) {
    const float* node_state = (const float*)d_in[0];
    const int* ei   = (const int*)d_in[1];
    const int* oe   = (const int*)d_in[2];
    const int* sidx = (const int*)d_in[3];
    const float* W1 = (const float*)d_in[4];
    const float* b1 = (const float*)d_in[5];
    const float* W2 = (const float*)d_in[6];
    const float* b2 = (const float*)d_in[7];
    const float* dW = (const float*)d_in[8];
    const float* db = (const float*)d_in[9];
    const float* oW = (const float*)d_in[10];
    const float* ob = (const float*)d_in[11];
    float* out = (float*)d_out;

    char* ws = (char*)d_ws;
    size_t off = 0;
    auto carve = [&](size_t bytes) -> char* {
        char* p = ws + off;
        off = (off + bytes + 255) & ~(size_t)255;
        return p;
    };
    int*   deg_in  = (int*)carve((size_t)NN * 4);
    float* r       = (float*)carve((size_t)2 * NN * 4);
    int*   row_ptr = (int*)carve((size_t)(NN + 1) * 4);
    int*   col     = (int*)carve((size_t)NE * 4);
    unsigned int* P_hist = (unsigned int*)carve((size_t)2 * NBH * NW * 4);
    int*   basetab = (int*)carve((size_t)NBH * NN * 4);
    unsigned short* t   = (unsigned short*)carve((size_t)NN * DD * 2);
    unsigned short* h   = (unsigned short*)carve((size_t)NN * DD * 2);
    unsigned short* BT1 = (unsigned short*)carve((size_t)DD * DD * 2);
    unsigned short* BT2 = (unsigned short*)carve((size_t)DD * DD * 2);
    unsigned short* BTd = (unsigned short*)carve((size_t)DD * NU * 2);
    float* P = (float*)t;   // alias: t dead after second aggregate

    float* r_out = r;
    float* r_in  = r + NN;

    // CSR build — no global atomics
    k_hist<<<dim3(NBH, 2), 256, 0, stream>>>(ei, P_hist);
    k_reduce<<<(2 * NW + 255) / 256, 256, 0, stream>>>(P_hist, deg_in, r);
    k_scan<<<1, 1024, 0, stream>>>(deg_in, row_ptr);
    k_colscan<<<(NN + 255) / 256, 256, 0, stream>>>(P_hist + (size_t)NBH * NW, row_ptr, basetab);
    k_bucket2<<<NBH, 256, 0, stream>>>(ei, basetab, col);

    // weight prep (single kernel)
    k_castW<<<256, 256, 0, stream>>>(W1, W2, dW, BT1, BT2, BTd);

    // layer 1
    k_gemm_bf<false><<<NB64, 256, 0, stream>>>(node_state, r_out, BT1, t);
    k_aggregate<<<(NN + 15) / 16, 256, 0, stream>>>(t, row_ptr, col, r_in, b1, h);

    // layer 2
    k_gemm_bf<true><<<NB64, 256, 0, stream>>>(h, r_out, BT2, t);
    k_aggregate<<<(NN + 15) / 16, 256, 0, stream>>>(t, row_ptr, col, r_in, b2, h);

    // per-node MLP + softmax, then gather
    k_mlp_mfma<<<NB64, 256, 0, stream>>>(h, BTd, db, oW, ob, P);
    k_gather<<<(NS + 255) / 256, 256, 0, stream>>>(sidx, oe, P, out);
}